// Round 5
// baseline (152.950 us; speedup 1.0000x reference)
//
#include <hip/hip_runtime.h>
#include <hip/hip_bf16.h>

// One-hot: label (H*W int32) -> out (N, H, W) float32.
// Memory-bound: ideal traffic = 64 MiB read + 512 MiB write.
//
// R1 (8 plane-streams per wave, read-once):     130 us = 4.63 TB/s  (write-stream aliasing)
// R3 (nontemporal stores):                      250 us  (nt bypasses L2 write-combine - never again)
// R4 (plane per blockIdx.y, contiguous writes): 146 us  (~6.3 TB/s BUT ~310MB label re-fetch, L3 thrash)
//
// R5: one block = 8 waves; wave w owns plane w. Block reads ONE 16 KiB label
// chunk (HBM once, L1/L2 for the other 7 waves); each wave writes its plane
// chunk as a single contiguous stream (R4's efficient pattern). Waves are
// staggered 2 KiB apart in-chunk to decorrelate the 64MiB-plane channel alias.
#define CHUNK 4096   // pixels per block
#define ITERS 16     // CHUNK / (64 lanes * 4 px)

__global__ void __launch_bounds__(512) get_one_hot_59442347376951_kernel(
    const int* __restrict__ label, float* __restrict__ out,
    int total /* H*W */) {
    const int w    = threadIdx.x >> 6;   // wave id = plane id (0..7)
    const int lane = threadIdx.x & 63;

    const long long base      = (long long)blockIdx.x * CHUNK;
    const long long planeBase = (long long)w * total;

    for (int it = 0; it < ITERS; ++it) {
        int j = (it + 2 * w) & (ITERS - 1);           // per-wave 2 KiB stagger
        long long idx = base + j * 256 + lane * 4;

        int4 lab = *reinterpret_cast<const int4*>(label + idx);

        float4 v;
        v.x = (lab.x == w) ? 1.0f : 0.0f;
        v.y = (lab.y == w) ? 1.0f : 0.0f;
        v.z = (lab.z == w) ? 1.0f : 0.0f;
        v.w = (lab.w == w) ? 1.0f : 0.0f;

        *reinterpret_cast<float4*>(out + planeBase + idx) = v;
    }
}

// Generic fallback (R1 structure) in case N != 8.
__global__ void __launch_bounds__(256) get_one_hot_generic_kernel(
    const int* __restrict__ label, float* __restrict__ out,
    int total, int N) {
    long long i = ((long long)blockIdx.x * blockDim.x + threadIdx.x) * 4;
    if (i >= total) return;
    int4 lab = *reinterpret_cast<const int4*>(label + i);
    for (int n = 0; n < N; ++n) {
        float4 v;
        v.x = (lab.x == n) ? 1.0f : 0.0f;
        v.y = (lab.y == n) ? 1.0f : 0.0f;
        v.z = (lab.z == n) ? 1.0f : 0.0f;
        v.w = (lab.w == n) ? 1.0f : 0.0f;
        *reinterpret_cast<float4*>(out + (long long)n * total + i) = v;
    }
}

extern "C" void kernel_launch(void* const* d_in, const int* in_sizes, int n_in,
                              void* d_out, int out_size, void* d_ws, size_t ws_size,
                              hipStream_t stream) {
    const int* label = (const int*)d_in[0];
    float* out = (float*)d_out;

    int total = in_sizes[0];          // H*W = 16,777,216
    int N = out_size / total;         // 8

    if (N == 8 && total % CHUNK == 0) {
        int grid = total / CHUNK;     // 4096 blocks x 512 threads
        get_one_hot_59442347376951_kernel<<<grid, 512, 0, stream>>>(label, out, total);
    } else {
        int grid = (total / 4 + 255) / 256;
        get_one_hot_generic_kernel<<<grid, 256, 0, stream>>>(label, out, total, N);
    }
}